// Round 3
// baseline (144.435 us; speedup 1.0000x reference)
//
#include <hip/hip_runtime.h>

// Row-wise dot product: out[n] = sum_d x[n][d] * y[n][d]
// N = 16384 rows, D = 1024 cols, fp32 in / fp32 out.
//
// R2: persistent-ish shape. 1024 blocks x 4 waves; each wave owns 4 rows,
// processed as 2 batches of 2 rows. Each batch issues 16 independent float4
// loads (clustered -> deep MLP; __launch_bounds__(256,4) gives 128 VGPR
// budget so the compiler can keep all 16 in flight), then two interleaved
// wave-reduce chains, then one float2 store (row pair is contiguous).

#define D 1024

__global__ __launch_bounds__(256, 4) void rowdot_kernel(const float* __restrict__ x,
                                                        const float* __restrict__ y,
                                                        float* __restrict__ out) {
    const int wave = threadIdx.x >> 6;
    const int lane = threadIdx.x & 63;
    // each wave owns 4 consecutive rows
    const int row0 = (blockIdx.x * 4 + wave) * 4;

    #pragma unroll
    for (int i = 0; i < 4; i += 2) {
        const int r = row0 + i;
        const float4* __restrict__ xr0 = (const float4*)(x + (size_t)r * D);
        const float4* __restrict__ yr0 = (const float4*)(y + (size_t)r * D);
        const float4* __restrict__ xr1 = (const float4*)(x + (size_t)(r + 1) * D);
        const float4* __restrict__ yr1 = (const float4*)(y + (size_t)(r + 1) * D);

        float4 a[4], b[4], c[4], d[4];
        // 16 independent loads, clustered before any use
        #pragma unroll
        for (int j = 0; j < 4; ++j) a[j] = xr0[lane + 64 * j];
        #pragma unroll
        for (int j = 0; j < 4; ++j) b[j] = yr0[lane + 64 * j];
        #pragma unroll
        for (int j = 0; j < 4; ++j) c[j] = xr1[lane + 64 * j];
        #pragma unroll
        for (int j = 0; j < 4; ++j) d[j] = yr1[lane + 64 * j];

        float s0 = 0.0f, s1 = 0.0f;
        #pragma unroll
        for (int j = 0; j < 4; ++j) {
            s0 += a[j].x * b[j].x + a[j].y * b[j].y + a[j].z * b[j].z + a[j].w * b[j].w;
            s1 += c[j].x * d[j].x + c[j].y * d[j].y + c[j].z * d[j].z + c[j].w * d[j].w;
        }

        // two interleaved wave-64 reduction chains
        #pragma unroll
        for (int off = 32; off > 0; off >>= 1) {
            s0 += __shfl_down(s0, off, 64);
            s1 += __shfl_down(s1, off, 64);
        }

        if (lane == 0) {
            *(float2*)(out + r) = make_float2(s0, s1);
        }
    }
}

extern "C" void kernel_launch(void* const* d_in, const int* in_sizes, int n_in,
                              void* d_out, int out_size, void* d_ws, size_t ws_size,
                              hipStream_t stream) {
    const float* x = (const float*)d_in[0];
    const float* y = (const float*)d_in[1];
    float* out = (float*)d_out;
    const int N = out_size;  // 16384 rows

    // N/4 rows-per-wave/4 waves-per-block = 1024 blocks = 4 blocks/CU
    rowdot_kernel<<<N / 16, 256, 0, stream>>>(x, y, out);
}

// Round 4
// 135.252 us; speedup vs baseline: 1.0679x; 1.0679x over previous
//
#include <hip/hip_runtime.h>

// Row-wise dot product: out[n] = sum_d x[n][d] * y[n][d]
// N = 16384 rows, D = 1024 cols, fp32 in / fp32 out.
//
// R3: force-clustered loads. R0-R2 all delivered exactly ~3.1 TB/s read BW
// regardless of wave count / structure; VGPR counts (20/40) prove the
// compiler never kept more than ~4 loads in flight per wave. This round:
// 2 rows per wave, 16 independent nontemporal 16B loads issued BEFORE an
// asm memory barrier (so all 16 are in flight; s_waitcnt drains
// progressively as FMAs consume them). 64 payload VGPRs expected ->
// VGPR_Count ~80-100. If BW still pins at 3.1 TB/s with proven 16-deep
// MLP, the read path itself is the ceiling.

#define D 1024

typedef float v4f __attribute__((ext_vector_type(4)));

__global__ __launch_bounds__(256) void rowdot_kernel(const float* __restrict__ x,
                                                     const float* __restrict__ y,
                                                     float* __restrict__ out) {
    const int wave = threadIdx.x >> 6;
    const int lane = threadIdx.x & 63;
    const int w = blockIdx.x * 4 + wave;  // global wave id
    const int r0 = w * 2;                 // two consecutive rows per wave

    const v4f* __restrict__ x0 = (const v4f*)(x + (size_t)r0 * D);
    const v4f* __restrict__ y0 = (const v4f*)(y + (size_t)r0 * D);
    const v4f* __restrict__ x1 = (const v4f*)(x + (size_t)(r0 + 1) * D);
    const v4f* __restrict__ y1 = (const v4f*)(y + (size_t)(r0 + 1) * D);

    // 16 independent loads, pinned before any use by the barrier below.
    v4f a0 = __builtin_nontemporal_load(&x0[lane]);
    v4f a1 = __builtin_nontemporal_load(&x0[lane + 64]);
    v4f a2 = __builtin_nontemporal_load(&x0[lane + 128]);
    v4f a3 = __builtin_nontemporal_load(&x0[lane + 192]);
    v4f b0 = __builtin_nontemporal_load(&y0[lane]);
    v4f b1 = __builtin_nontemporal_load(&y0[lane + 64]);
    v4f b2 = __builtin_nontemporal_load(&y0[lane + 128]);
    v4f b3 = __builtin_nontemporal_load(&y0[lane + 192]);
    v4f c0 = __builtin_nontemporal_load(&x1[lane]);
    v4f c1 = __builtin_nontemporal_load(&x1[lane + 64]);
    v4f c2 = __builtin_nontemporal_load(&x1[lane + 128]);
    v4f c3 = __builtin_nontemporal_load(&x1[lane + 192]);
    v4f d0 = __builtin_nontemporal_load(&y1[lane]);
    v4f d1 = __builtin_nontemporal_load(&y1[lane + 64]);
    v4f d2 = __builtin_nontemporal_load(&y1[lane + 128]);
    v4f d3 = __builtin_nontemporal_load(&y1[lane + 192]);

    // Compiler barrier: all 16 loads must be issued before anything below.
    asm volatile("" ::: "memory");

    float s0 = 0.0f, s1 = 0.0f;
    s0 += a0.x * b0.x + a0.y * b0.y + a0.z * b0.z + a0.w * b0.w;
    s0 += a1.x * b1.x + a1.y * b1.y + a1.z * b1.z + a1.w * b1.w;
    s0 += a2.x * b2.x + a2.y * b2.y + a2.z * b2.z + a2.w * b2.w;
    s0 += a3.x * b3.x + a3.y * b3.y + a3.z * b3.z + a3.w * b3.w;
    s1 += c0.x * d0.x + c0.y * d0.y + c0.z * d0.z + c0.w * d0.w;
    s1 += c1.x * d1.x + c1.y * d1.y + c1.z * d1.z + c1.w * d1.w;
    s1 += c2.x * d2.x + c2.y * d2.y + c2.z * d2.z + c2.w * d2.w;
    s1 += c3.x * d3.x + c3.y * d3.y + c3.z * d3.z + c3.w * d3.w;

    // two interleaved wave-64 reduction chains
    #pragma unroll
    for (int off = 32; off > 0; off >>= 1) {
        s0 += __shfl_down(s0, off, 64);
        s1 += __shfl_down(s1, off, 64);
    }

    if (lane == 0) {
        *(float2*)(out + r0) = make_float2(s0, s1);
    }
}

extern "C" void kernel_launch(void* const* d_in, const int* in_sizes, int n_in,
                              void* d_out, int out_size, void* d_ws, size_t ws_size,
                              hipStream_t stream) {
    const float* x = (const float*)d_in[0];
    const float* y = (const float*)d_in[1];
    float* out = (float*)d_out;
    const int N = out_size;  // 16384 rows

    // 2 rows per wave, 4 waves per block -> 8 rows per block
    rowdot_kernel<<<N / 8, 256, 0, stream>>>(x, y, out);
}